// Round 1
// baseline (294.014 us; speedup 1.0000x reference)
//
#include <hip/hip_runtime.h>

#define B_   8192
#define T_   256
#define F_   18
#define U_   32
#define NIDS 1000

// ---------------------------------------------------------------------------
// Phase 1: for each (t, id) find the LAST batch index b with id(b,t)==id.
// (.at[ids].set semantics: last occurrence wins -> max b.)
// ---------------------------------------------------------------------------
__global__ __launch_bounds__(256) void find_winners(
    const float* __restrict__ inputs, int* __restrict__ winner)
{
    int idx = blockIdx.x * 256 + threadIdx.x;      // idx = b*T_ + t  (T_=256)
    float fid = inputs[(size_t)idx * F_];          // feature 0 = id as float
    int id = (int)fid;
    id = id < 0 ? 0 : (id >= NIDS ? NIDS - 1 : id);
    int t = idx & (T_ - 1);
    int b = idx >> 8;
    atomicMax(&winner[t * NIDS + id], b);
}

// ---------------------------------------------------------------------------
// GRU step, one wave per chain. lane = (j, kh): unit j = lane&31, half kh.
// h[16]  : replicated h values for this half's k-range [16*kh, 16*kh+16)
// hown   : h_j (this lane's own unit)
// xv[9]  : x values k in [9*kh, 9*kh+9)
// Returns h_new_j (valid in all 64 lanes after internal combines).
// ---------------------------------------------------------------------------
__device__ __forceinline__ float gru_step(
    const float (&h)[16], float hown, const float (&xv)[9],
    const float (&Wz)[16], const float (&Wr)[16], const float (&Wh)[16],
    const float (&Kz)[9],  const float (&Kr)[9],  const float (&Kh)[9],
    float bz, float br, float bh, int kh, bool valid)
{
    float az = 0.f, ar = 0.f;
#pragma unroll
    for (int kk = 0; kk < 16; ++kk) {
        az = fmaf(h[kk], Wz[kk], az);
        ar = fmaf(h[kk], Wr[kk], ar);
    }
#pragma unroll
    for (int q = 0; q < 9; ++q) {
        az = fmaf(xv[q], Kz[q], az);
        ar = fmaf(xv[q], Kr[q], ar);
    }
    az += __shfl_xor(az, 32, 64);   // combine halves -> full dot in all lanes
    ar += __shfl_xor(ar, 32, 64);
    float z = fminf(fmaxf(fmaf(az + bz, 0.2f, 0.5f), 0.f), 1.f);
    float r = fminf(fmaxf(fmaf(ar + br, 0.2f, 0.5f), 0.f), 1.f);
    float p = r * hown;             // p_j = r_j * h_j  (lane's own unit)
    float ah = 0.f;
#pragma unroll
    for (int kk = 0; kk < 16; ++kk) {
        float pk = __shfl(p, kh * 16 + kk, 64);   // p for unit 16*kh+kk
        ah = fmaf(pk, Wh[kk], ah);
    }
#pragma unroll
    for (int q = 0; q < 9; ++q) ah = fmaf(xv[q], Kh[q], ah);
    ah += __shfl_xor(ah, 32, 64);
    float hh = tanhf(ah + bh);
    float hnew = z * hown + (1.f - z) * hh;
    return valid ? hnew : hown;
}

__device__ __forceinline__ void advance_h(
    float (&h)[16], float& hown, float hnewj, int kh, int j)
{
#pragma unroll
    for (int kk = 0; kk < 16; ++kk) h[kk] = __shfl(hnewj, kh * 16 + kk, 64);
    hown = __shfl(hnewj, j, 64);
}

__device__ __forceinline__ void loadrow(
    float (&xv)[9], const float* __restrict__ inputs, int w, int t, int kh)
{
    if (w >= 0) {
        const float* p = inputs + ((size_t)w * T_ + t) * F_ + kh * 9;
#pragma unroll
        for (int q = 0; q < 9; ++q) xv[q] = p[q];
    } else {
#pragma unroll
        for (int q = 0; q < 9; ++q) xv[q] = 0.f;
    }
}

// ---------------------------------------------------------------------------
// Phase 2: 1000 chains, one wave each (4 waves / block, 250 blocks).
// Runs steps t = 0..254 and writes the state table as of the start of t=255.
// ---------------------------------------------------------------------------
__global__ __launch_bounds__(256) void run_chains(
    const float* __restrict__ inputs, const float* __restrict__ K,
    const float* __restrict__ R, const float* __restrict__ bias,
    const float* __restrict__ sinit, const int* __restrict__ winner,
    float* __restrict__ table)
{
    __shared__ int wlds[4][256];
    int tid = threadIdx.x;
    int chain0 = blockIdx.x * 4;
    for (int idx = tid; idx < 4 * 256; idx += 256) {
        int c = idx >> 8;
        int t = idx & 255;
        wlds[c][t] = (t < T_ - 1) ? winner[t * NIDS + chain0 + c] : -1;
    }
    __syncthreads();

    int wv = tid >> 6, lane = tid & 63;
    int j = lane & 31, kh = lane >> 5;
    int chain = chain0 + wv;

    float Wz[16], Wr[16], Wh[16];
#pragma unroll
    for (int kk = 0; kk < 16; ++kk) {
        int k = kh * 16 + kk;
        Wz[kk] = R[k * 96 + j];
        Wr[kk] = R[k * 96 + 32 + j];
        Wh[kk] = R[k * 96 + 64 + j];
    }
    float Kz[9], Kr[9], Kh[9];
#pragma unroll
    for (int q = 0; q < 9; ++q) {
        int k = kh * 9 + q;
        Kz[q] = K[k * 96 + j];
        Kr[q] = K[k * 96 + 32 + j];
        Kh[q] = K[k * 96 + 64 + j];
    }
    float bz = bias[j], br = bias[32 + j], bh = bias[64 + j];

    float h[16], hown;
#pragma unroll
    for (int kk = 0; kk < 16; ++kk) h[kk] = sinit[chain * U_ + kh * 16 + kk];
    hown = sinit[chain * U_ + j];

    // software pipeline: 3 x-row buffers, prefetch 3 steps ahead
    float xA[9], xB[9], xC[9];
    int wA = wlds[wv][0]; loadrow(xA, inputs, wA, 0, kh);
    int wB = wlds[wv][1]; loadrow(xB, inputs, wB, 1, kh);
    int wC = wlds[wv][2]; loadrow(xC, inputs, wC, 2, kh);

    for (int t = 0; t < 255; t += 3) {   // 255 steps, 85 iterations
        {
            float hn = gru_step(h, hown, xA, Wz, Wr, Wh, Kz, Kr, Kh, bz, br, bh, kh, wA >= 0);
            advance_h(h, hown, hn, kh, j);
            int tt = t + 3; tt = tt > 254 ? 254 : tt;
            wA = wlds[wv][tt]; loadrow(xA, inputs, wA, tt, kh);
        }
        {
            float hn = gru_step(h, hown, xB, Wz, Wr, Wh, Kz, Kr, Kh, bz, br, bh, kh, wB >= 0);
            advance_h(h, hown, hn, kh, j);
            int tt = t + 4; tt = tt > 254 ? 254 : tt;
            wB = wlds[wv][tt]; loadrow(xB, inputs, wB, tt, kh);
        }
        {
            float hn = gru_step(h, hown, xC, Wz, Wr, Wh, Kz, Kr, Kh, bz, br, bh, kh, wC >= 0);
            advance_h(h, hown, hn, kh, j);
            int tt = t + 5; tt = tt > 254 ? 254 : tt;
            wC = wlds[wv][tt]; loadrow(xC, inputs, wC, tt, kh);
        }
    }

    if (kh == 0) table[chain * U_ + j] = hown;   // state entering t=255
}

// ---------------------------------------------------------------------------
// Phase 3: final step t=255 for all 8192 batch elements + MLP + sigmoid.
// One wave per element, 8 elements per wave, 4 waves per block, 256 blocks.
// ---------------------------------------------------------------------------
__global__ __launch_bounds__(256) void finalize(
    const float* __restrict__ inputs, const float* __restrict__ K,
    const float* __restrict__ R, const float* __restrict__ bias,
    const float* __restrict__ table, const float* __restrict__ w1,
    const float* __restrict__ b1, const float* __restrict__ w2,
    const float* __restrict__ b2, float* __restrict__ out)
{
    int tid = threadIdx.x;
    int wv = tid >> 6, lane = tid & 63;
    int j = lane & 31, kh = lane >> 5;

    float Wz[16], Wr[16], Wh[16], w1c[16];
#pragma unroll
    for (int kk = 0; kk < 16; ++kk) {
        int k = kh * 16 + kk;
        Wz[kk]  = R[k * 96 + j];
        Wr[kk]  = R[k * 96 + 32 + j];
        Wh[kk]  = R[k * 96 + 64 + j];
        w1c[kk] = w1[k * 32 + j];
    }
    float Kz[9], Kr[9], Kh[9];
#pragma unroll
    for (int q = 0; q < 9; ++q) {
        int k = kh * 9 + q;
        Kz[q] = K[k * 96 + j];
        Kr[q] = K[k * 96 + 32 + j];
        Kh[q] = K[k * 96 + 64 + j];
    }
    float bz = bias[j], br = bias[32 + j], bh = bias[64 + j];
    float b1v = b1[j], w2v = w2[j], b2v = b2[0];

    int b0 = (blockIdx.x * 4 + wv) * 8;
    for (int bb = 0; bb < 8; ++bb) {
        int b = b0 + bb;
        const float* row = inputs + ((size_t)b * T_ + (T_ - 1)) * F_;
        int id = (int)row[0];
        float xv[9];
#pragma unroll
        for (int q = 0; q < 9; ++q) xv[q] = row[kh * 9 + q];
        float h[16], hown;
#pragma unroll
        for (int kk = 0; kk < 16; ++kk) h[kk] = table[id * U_ + kh * 16 + kk];
        hown = table[id * U_ + j];

        float hn = gru_step(h, hown, xv, Wz, Wr, Wh, Kz, Kr, Kh, bz, br, bh, kh, true);
        advance_h(h, hown, hn, kh, j);   // h[] now holds h_new half

        float am = 0.f;
#pragma unroll
        for (int kk = 0; kk < 16; ++kk) am = fmaf(h[kk], w1c[kk], am);
        am += __shfl_xor(am, 32, 64);
        float hid = fmaxf(am + b1v, 0.f);          // relu(last @ w1 + b1), unit j
        float p = (kh == 0) ? hid * w2v : 0.f;     // count each unit once
#pragma unroll
        for (int s = 1; s < 64; s <<= 1) p += __shfl_xor(p, s, 64);
        if (lane == 0) out[b] = 1.f / (1.f + expf(-(p + b2v)));
    }
}

// ---------------------------------------------------------------------------
extern "C" void kernel_launch(void* const* d_in, const int* in_sizes, int n_in,
                              void* d_out, int out_size, void* d_ws, size_t ws_size,
                              hipStream_t stream)
{
    const float* inputs = (const float*)d_in[0];
    const float* K      = (const float*)d_in[1];
    const float* R      = (const float*)d_in[2];
    const float* bias   = (const float*)d_in[3];
    const float* sinit  = (const float*)d_in[4];
    const float* w1     = (const float*)d_in[5];
    const float* b1     = (const float*)d_in[6];
    const float* w2     = (const float*)d_in[7];
    const float* b2     = (const float*)d_in[8];
    float* out = (float*)d_out;

    int*   winner = (int*)d_ws;                          // 256*1000*4 = 1,024,000 B
    float* table  = (float*)((char*)d_ws + (1 << 20));   // 1000*32*4  = 128,000 B

    hipMemsetAsync(winner, 0xFF, T_ * NIDS * sizeof(int), stream);  // -1
    find_winners<<<dim3((B_ * T_) / 256), dim3(256), 0, stream>>>(inputs, winner);
    run_chains<<<dim3(NIDS / 4), dim3(256), 0, stream>>>(inputs, K, R, bias, sinit, winner, table);
    finalize<<<dim3(B_ / 32), dim3(256), 0, stream>>>(inputs, K, R, bias, table, w1, b1, w2, b2, out);
}